// Round 2
// baseline (1026.343 us; speedup 1.0000x reference)
//
#include <hip/hip_runtime.h>

#define HID 256
#define TLEN 1024
#define BATCH 128

typedef _Float16 half2_t __attribute__((ext_vector_type(2)));

__device__ __forceinline__ float fexp2(float x) { return __builtin_amdgcn_exp2f(x); }
__device__ __forceinline__ float frcp(float x)  { return __builtin_amdgcn_rcpf(x); }
__device__ __forceinline__ float fast_sigmoid(float x) {
  return frcp(1.0f + fexp2(-1.442695040888963f * x));
}
__device__ __forceinline__ float fast_tanh(float x) {
  float e = fexp2(2.885390081777927f * x);
  return 1.0f - 2.0f * frcp(e + 1.0f);
}
__device__ __forceinline__ float dot2acc(half2_t a, half2_t b, float c) {
  return __builtin_amdgcn_fdot2(a, b, c, false);   // v_dot2_f32_f16
}

#if defined(__has_builtin) && __has_builtin(__builtin_amdgcn_sdot4)
#define SDOT4(a, b, c) __builtin_amdgcn_sdot4((int)(a), (int)(b), (c), false)
#else
__device__ __forceinline__ int SDOT4(int a, int b, int c) {
#pragma unroll
  for (int e = 0; e < 4; ++e)
    c += ((a << (24 - 8 * e)) >> 24) * ((b << (24 - 8 * e)) >> 24);
  return c;
}
#endif

// DPP (VALU pipe). Verified on this HW in earlier rounds.
#define DPP_ADD_F(var, ctrl, rmask)                                            \
  var += __builtin_bit_cast(float, __builtin_amdgcn_update_dpp(                \
      0, __builtin_bit_cast(int, var), (ctrl), (rmask), 0xf, true))
#define DPP_ADD_I(var, ctrl, rmask)                                            \
  var += __builtin_amdgcn_update_dpp(0, (var), (ctrl), (rmask), 0xf, true)

__device__ __forceinline__ float wave_sum63_f(float p) {
  DPP_ADD_F(p, 0x111, 0xf);
  DPP_ADD_F(p, 0x112, 0xf);
  DPP_ADD_F(p, 0x114, 0xf);
  DPP_ADD_F(p, 0x118, 0xf);
  DPP_ADD_F(p, 0x142, 0xa);
  DPP_ADD_F(p, 0x143, 0xc);   // -> lane63 has wave total
  return p;
}
__device__ __forceinline__ int wave_sum63_i(int p) {
  DPP_ADD_I(p, 0x111, 0xf);
  DPP_ADD_I(p, 0x112, 0xf);
  DPP_ADD_I(p, 0x114, 0xf);
  DPP_ADD_I(p, 0x118, 0xf);
  DPP_ADD_I(p, 0x142, 0xa);
  DPP_ADD_I(p, 0x143, 0xc);   // -> lane63 has wave total (exact, int)
  return p;
}

// ---- prep: per-row i8 quant of W_hh (768x256), layout wq[row*16 + c]
// (row-contiguous so persistent thread r loads 16 consecutive uint4);
// plus i8 pack of Wb_h with folded scale so hWb = sdot_total * wbscale.
__global__ void quant_whh(const float* __restrict__ W_hh,
                          const float* __restrict__ Wb_h,
                          uint4* __restrict__ wq,
                          float* __restrict__ scales,
                          unsigned* __restrict__ wbq,
                          float* __restrict__ wbscale) {
  const int r = blockIdx.x * 256 + threadIdx.x;   // 0..1023
  if (r < 768) {
    const float* row = W_hh + (size_t)r * HID;
    float amax = 0.0f;
    for (int k = 0; k < HID; ++k) amax = fmaxf(amax, fabsf(row[k]));
    amax = fmaxf(amax, 1e-20f);
    scales[r] = amax / 127.0f;
    const float inv = 127.0f / amax;
    for (int c = 0; c < 16; ++c) {
      unsigned w[4];
#pragma unroll
      for (int u = 0; u < 4; ++u) {
        unsigned bb = 0;
#pragma unroll
        for (int e = 0; e < 4; ++e) {
          int qv = (int)rintf(row[16 * c + 4 * u + e] * inv);
          bb |= (unsigned)(qv & 0xff) << (8 * e);
        }
        w[u] = bb;
      }
      wq[(size_t)r * 16 + c] = uint4{w[0], w[1], w[2], w[3]};
    }
  } else if (r < 832) {
    // threads 768..831: pack Wb_h word (r-768); amax computed redundantly
    float amax = 0.0f;
    for (int k = 0; k < HID; ++k) amax = fmaxf(amax, fabsf(Wb_h[k]));
    amax = fmaxf(amax, 1e-20f);
    const float inv = 127.0f / amax;
    const int i = r - 768;
    unsigned bb = 0;
#pragma unroll
    for (int e = 0; e < 4; ++e) {
      int qv = (int)rintf(Wb_h[4 * i + e] * inv);
      bb |= (unsigned)(qv & 0xff) << (8 * e);
    }
    wbq[i] = bb;
    if (i == 0) wbscale[0] = (amax / 127.0f) * (1.0f / 127.0f);
  }
}

// R15: gate-split persistent kernel, codegen fixed. 768 threads (12 waves,
// 3 waves/SIMD). Thread tid owns row tid of the 768x256 matvec: gate
// g = tid>>8, dim d = tid&255. 16 uint4 weights/thread HELD IN VGPRS:
// waves_per_eu(3,3) raises the regalloc budget to ~170 and an asm pin stops
// the compiler from sinking the loads into the loop (R14 failure: VGPR=52,
// weights re-read from L2 every step). hWb is computed per-wave in phase 1
// from i8 hq (ds_read + sdot4 + int DPP + readlane -- latency hides under the
// 64-sdot burst), so phase 2 is just: rz read -> tanh -> h' -> i8 store.
__global__
__attribute__((amdgpu_flat_work_group_size(768, 768)))
__attribute__((amdgpu_waves_per_eu(3, 3)))
void momgru_persistent(const float* __restrict__ x,
                       const float* __restrict__ W_ih,
                       const float* __restrict__ b_ih,
                       const float* __restrict__ b_hh,
                       const float* __restrict__ Wb_x,
                       const float* __restrict__ b_beta,
                       const float* __restrict__ s_ptr,
                       const float* __restrict__ W_head,
                       const float* __restrict__ b_head,
                       const uint4* __restrict__ wq,
                       const float* __restrict__ scales,
                       const unsigned* __restrict__ wbq,
                       const float* __restrict__ wbscale,
                       float* __restrict__ out)  // [0,128) head, [128,128+B*T) betas
{
  const int b    = blockIdx.x;
  const int tid  = threadIdx.x;   // row r of [768 x 256]
  const int lane = tid & 63;
  const int wv   = tid >> 6;      // 0..11
  const int g    = tid >> 8;      // 0=r,1=z,2=n (wave-uniform)
  const int d    = tid & 255;     // hidden dim

  __shared__ __align__(16) unsigned hq[64];   // h_t as i8 (single buffer)
  __shared__ float rz2[256][2];               // r,z gate values, paired per dim
  __shared__ float headred[4];

  // ---- weights: 16 uint4 per row, register-resident (pinned) ----
  const uint4* wqt = wq + (size_t)tid * 16;
  uint4 w[16];
#pragma unroll
  for (int j = 0; j < 16; ++j) w[j] = wqt[j];
#pragma unroll
  for (int j = 0; j < 16; ++j)
    asm volatile("" : "+v"(w[j].x), "+v"(w[j].y), "+v"(w[j].z), "+v"(w[j].w));

  // ---- per-thread constants (s pre-folded into input projection) ----
  const float sv = s_ptr[0];
  const half2_t wih2 = half2_t{(_Float16)(sv * W_ih[2 * tid]),
                               (_Float16)(sv * W_ih[2 * tid + 1])};
  const float bih = sv * b_ih[tid];
  const float bhh = b_hh[tid];
  const float sc  = scales[tid] * (1.0f / 127.0f);
  const half2_t wbx2 = half2_t{(_Float16)Wb_x[0], (_Float16)Wb_x[1]};  // uniform
  const float bbeta = b_beta[0];
  const unsigned wbq_l = wbq[lane];       // Wb_h i8, dims 4*lane..4*lane+3
  const float wbsc = wbscale[0];          // folded (amax/127)*(1/127)

  // ---- init ----
  if (tid < 64) hq[tid] = 0u;
  float v = 0.0f, h_old = 0.0f;
  float* betas = out + BATCH;
  const float2* xg2 = reinterpret_cast<const float2*>(x + (size_t)b * TLEN * 2);
  float2 xv = xg2[0];
  __syncthreads();

  for (int t = 0; t < TLEN; ++t) {
    // ---- phase 1a: per-wave hWb from h_{t-1} i8 words (hides under burst) --
    const unsigned hw_l = reinterpret_cast<const unsigned*>(hq)[lane];
    int hwb_i = SDOT4(hw_l, wbq_l, 0);
    hwb_i = wave_sum63_i(hwb_i);

    // ---- phase 1b: i8 matvec burst, 4 accumulators ----
    const int4* hb = reinterpret_cast<const int4*>(hq);   // 16 x int4, uniform
    int a0 = 0, a1 = 0, a2 = 0, a3 = 0;
#pragma unroll
    for (int c = 0; c < 4; ++c) {
      const int4 h0 = hb[4 * c + 0];
      const int4 h1 = hb[4 * c + 1];
      const int4 h2 = hb[4 * c + 2];
      const int4 h3 = hb[4 * c + 3];
      a0 = SDOT4(h0.x, w[4 * c + 0].x, a0);
      a1 = SDOT4(h1.x, w[4 * c + 1].x, a1);
      a2 = SDOT4(h2.x, w[4 * c + 2].x, a2);
      a3 = SDOT4(h3.x, w[4 * c + 3].x, a3);
      a0 = SDOT4(h0.y, w[4 * c + 0].y, a0);
      a1 = SDOT4(h1.y, w[4 * c + 1].y, a1);
      a2 = SDOT4(h2.y, w[4 * c + 2].y, a2);
      a3 = SDOT4(h3.y, w[4 * c + 3].y, a3);
      a0 = SDOT4(h0.z, w[4 * c + 0].z, a0);
      a1 = SDOT4(h1.z, w[4 * c + 1].z, a1);
      a2 = SDOT4(h2.z, w[4 * c + 2].z, a2);
      a3 = SDOT4(h3.z, w[4 * c + 3].z, a3);
      a0 = SDOT4(h0.w, w[4 * c + 0].w, a0);
      a1 = SDOT4(h1.w, w[4 * c + 1].w, a1);
      a2 = SDOT4(h2.w, w[4 * c + 2].w, a2);
      a3 = SDOT4(h3.w, w[4 * c + 3].w, a3);
    }
    const int a = (a0 + a1) + (a2 + a3);
    const float ga = fmaf((float)a, sc, bhh);       // hidden projection, this row

    // ---- phase 1c: beta + momentum + r/z sigma ----
    const float hWb = (float)__builtin_amdgcn_readlane(hwb_i, 63) * wbsc;
    const half2_t x2 = half2_t{(_Float16)xv.x, (_Float16)xv.y};
    xv = xg2[(t + 1 < TLEN) ? t + 1 : t];           // prefetch next x
    const float beta = fast_sigmoid(dot2acc(x2, wbx2, hWb + bbeta));
    v = beta * v + dot2acc(x2, wih2, bih);
    if (tid == 0) betas[(size_t)b * TLEN + t] = beta;

    if (g < 2) rz2[d][g] = fast_sigmoid(v + ga);    // r,z -> LDS
    __syncthreads();

    // ---- phase 2 (n-waves only): n, h', quantize ----
    if (g == 2) {
      const float2 rzv = *reinterpret_cast<const float2*>(&rz2[d][0]);  // b64
      const float n_ = fast_tanh(fmaf(rzv.x, ga, v));
      h_old = fmaf(rzv.y, h_old - n_, n_);          // (1-z)n + z h
      const int q = (int)rintf(h_old * 127.0f);
      reinterpret_cast<unsigned char*>(hq)[d] = (unsigned char)(q & 0xff);
    }
    __syncthreads();
  }

  // ---- head (h_T lives in the n-waves) ----
  if (g == 2) {
    float hp = h_old * W_head[d];
    hp = wave_sum63_f(hp);
    if (lane == 63) headred[wv - 8] = hp;
  }
  __syncthreads();
  if (tid == 0)
    out[b] = ((headred[0] + headred[1]) + (headred[2] + headred[3])) + b_head[0];
}

extern "C" void kernel_launch(void* const* d_in, const int* in_sizes, int n_in,
                              void* d_out, int out_size, void* d_ws, size_t ws_size,
                              hipStream_t stream) {
  const float* x      = (const float*)d_in[0];
  const float* W_ih   = (const float*)d_in[1];
  const float* W_hh   = (const float*)d_in[2];
  const float* b_ih   = (const float*)d_in[3];
  const float* b_hh   = (const float*)d_in[4];
  const float* Wb_x   = (const float*)d_in[5];
  const float* Wb_h   = (const float*)d_in[6];
  const float* b_beta = (const float*)d_in[7];
  const float* s      = (const float*)d_in[8];
  const float* W_head = (const float*)d_in[9];
  const float* b_head = (const float*)d_in[10];
  float* out = (float*)d_out;

  char* wsb = (char*)d_ws;
  uint4*    wq      = (uint4*)wsb;                 // 768*16*16 = 196608 B
  float*    scales  = (float*)(wsb + 196608);      // 768*4 = 3072 B
  unsigned* wbq     = (unsigned*)(wsb + 199680);   // 64*4 = 256 B
  float*    wbscale = (float*)(wsb + 199936);      // 4 B

  quant_whh<<<dim3(4), dim3(256), 0, stream>>>(W_hh, Wb_h, wq, scales, wbq, wbscale);
  momgru_persistent<<<dim3(BATCH), dim3(768), 0, stream>>>(
      x, W_ih, b_ih, b_hh, Wb_x, b_beta, s, W_head, b_head,
      (const uint4*)wq, (const float*)scales, (const unsigned*)wbq,
      (const float*)wbscale, out);
}

// Round 3
// 1025.691 us; speedup vs baseline: 1.0006x; 1.0006x over previous
//
#include <hip/hip_runtime.h>

#define HID 256
#define TLEN 1024
#define BATCH 128

typedef _Float16 half2_t __attribute__((ext_vector_type(2)));

__device__ __forceinline__ float fexp2(float x) { return __builtin_amdgcn_exp2f(x); }
__device__ __forceinline__ float frcp(float x)  { return __builtin_amdgcn_rcpf(x); }
__device__ __forceinline__ float fast_sigmoid(float x) {
  return frcp(1.0f + fexp2(-1.442695040888963f * x));
}
__device__ __forceinline__ float fast_tanh(float x) {
  float e = fexp2(2.885390081777927f * x);
  return 1.0f - 2.0f * frcp(e + 1.0f);
}
__device__ __forceinline__ float dot2acc(half2_t a, half2_t b, float c) {
  return __builtin_amdgcn_fdot2(a, b, c, false);   // v_dot2_f32_f16
}

#if defined(__has_builtin) && __has_builtin(__builtin_amdgcn_sdot4)
#define SDOT4(a, b, c) __builtin_amdgcn_sdot4((int)(a), (int)(b), (c), false)
#else
__device__ __forceinline__ int SDOT4(int a, int b, int c) {
#pragma unroll
  for (int e = 0; e < 4; ++e)
    c += ((a << (24 - 8 * e)) >> 24) * ((b << (24 - 8 * e)) >> 24);
  return c;
}
#endif

// DPP (VALU pipe). Verified on this HW in earlier rounds.
#define DPP_ADD_F(var, ctrl, rmask)                                            \
  var += __builtin_bit_cast(float, __builtin_amdgcn_update_dpp(                \
      0, __builtin_bit_cast(int, var), (ctrl), (rmask), 0xf, true))
#define DPP_ADD_I(var, ctrl, rmask)                                            \
  var += __builtin_amdgcn_update_dpp(0, (var), (ctrl), (rmask), 0xf, true)

__device__ __forceinline__ float wave_sum63_f(float p) {
  DPP_ADD_F(p, 0x111, 0xf);
  DPP_ADD_F(p, 0x112, 0xf);
  DPP_ADD_F(p, 0x114, 0xf);
  DPP_ADD_F(p, 0x118, 0xf);
  DPP_ADD_F(p, 0x142, 0xa);
  DPP_ADD_F(p, 0x143, 0xc);   // -> lane63 has wave total
  return p;
}
__device__ __forceinline__ int wave_sum63_i(int p) {
  DPP_ADD_I(p, 0x111, 0xf);
  DPP_ADD_I(p, 0x112, 0xf);
  DPP_ADD_I(p, 0x114, 0xf);
  DPP_ADD_I(p, 0x118, 0xf);
  DPP_ADD_I(p, 0x142, 0xa);
  DPP_ADD_I(p, 0x143, 0xc);   // -> lane63 has wave total (exact, int)
  return p;
}

// ---- prep: per-row i8 quant of W_hh (768x256), layout wq[row*16 + c]
// (row-contiguous so persistent thread r loads 16 consecutive uint4);
// plus i8 pack of Wb_h with folded scale so hWb = sdot_total * wbscale.
__global__ void quant_whh(const float* __restrict__ W_hh,
                          const float* __restrict__ Wb_h,
                          uint4* __restrict__ wq,
                          float* __restrict__ scales,
                          unsigned* __restrict__ wbq,
                          float* __restrict__ wbscale) {
  const int r = blockIdx.x * 256 + threadIdx.x;   // 0..1023
  if (r < 768) {
    const float* row = W_hh + (size_t)r * HID;
    float amax = 0.0f;
    for (int k = 0; k < HID; ++k) amax = fmaxf(amax, fabsf(row[k]));
    amax = fmaxf(amax, 1e-20f);
    scales[r] = amax / 127.0f;
    const float inv = 127.0f / amax;
    for (int c = 0; c < 16; ++c) {
      unsigned w[4];
#pragma unroll
      for (int u = 0; u < 4; ++u) {
        unsigned bb = 0;
#pragma unroll
        for (int e = 0; e < 4; ++e) {
          int qv = (int)rintf(row[16 * c + 4 * u + e] * inv);
          bb |= (unsigned)(qv & 0xff) << (8 * e);
        }
        w[u] = bb;
      }
      wq[(size_t)r * 16 + c] = uint4{w[0], w[1], w[2], w[3]};
    }
  } else if (r < 832) {
    // threads 768..831: pack Wb_h word (r-768); amax computed redundantly
    float amax = 0.0f;
    for (int k = 0; k < HID; ++k) amax = fmaxf(amax, fabsf(Wb_h[k]));
    amax = fmaxf(amax, 1e-20f);
    const float inv = 127.0f / amax;
    const int i = r - 768;
    unsigned bb = 0;
#pragma unroll
    for (int e = 0; e < 4; ++e) {
      int qv = (int)rintf(Wb_h[4 * i + e] * inv);
      bb |= (unsigned)(qv & 0xff) << (8 * e);
    }
    wbq[i] = bb;
    if (i == 0) wbscale[0] = (amax / 127.0f) * (1.0f / 127.0f);
  }
}

// R16: gate-split persistent kernel, weight residency FORCED. 768 threads
// (12 waves, 3 waves/SIMD). Thread tid owns row tid of the 768x256 matvec.
// R15 failure: a one-time asm pin before the loop let the compiler
// rematerialize the 16 uint4 weight loads inside the loop (VGPR=76, 196KB
// re-read from L2 per block per step, ~77% of L2 ceiling). Fix: empty
// `asm volatile "+v"` on all 64 weight dwords INSIDE the loop -- each weight
// becomes a loop-carried register the asm "may modify", so a reload from
// memory is illegal and the allocator must keep them in VGPRs (budget 170 at
// waves_per_eu(3,3), need ~110).
__global__
__attribute__((amdgpu_flat_work_group_size(768, 768)))
__attribute__((amdgpu_waves_per_eu(3, 3)))
void momgru_persistent(const float* __restrict__ x,
                       const float* __restrict__ W_ih,
                       const float* __restrict__ b_ih,
                       const float* __restrict__ b_hh,
                       const float* __restrict__ Wb_x,
                       const float* __restrict__ b_beta,
                       const float* __restrict__ s_ptr,
                       const float* __restrict__ W_head,
                       const float* __restrict__ b_head,
                       const uint4* __restrict__ wq,
                       const float* __restrict__ scales,
                       const unsigned* __restrict__ wbq,
                       const float* __restrict__ wbscale,
                       float* __restrict__ out)  // [0,128) head, [128,128+B*T) betas
{
  const int b    = blockIdx.x;
  const int tid  = threadIdx.x;   // row r of [768 x 256]
  const int lane = tid & 63;
  const int wv   = tid >> 6;      // 0..11
  const int g    = tid >> 8;      // 0=r,1=z,2=n (wave-uniform)
  const int d    = tid & 255;     // hidden dim

  __shared__ __align__(16) unsigned hq[64];   // h_t as i8 (single buffer)
  __shared__ float rz2[256][2];               // r,z gate values, paired per dim
  __shared__ float headred[4];

  // ---- weights: 16 uint4 per row, register-resident ----
  const uint4* wqt = wq + (size_t)tid * 16;
  uint4 w[16];
#pragma unroll
  for (int j = 0; j < 16; ++j) w[j] = wqt[j];

  // ---- per-thread constants (s pre-folded into input projection) ----
  const float sv = s_ptr[0];
  const half2_t wih2 = half2_t{(_Float16)(sv * W_ih[2 * tid]),
                               (_Float16)(sv * W_ih[2 * tid + 1])};
  const float bih = sv * b_ih[tid];
  const float bhh = b_hh[tid];
  const float sc  = scales[tid] * (1.0f / 127.0f);
  const half2_t wbx2 = half2_t{(_Float16)Wb_x[0], (_Float16)Wb_x[1]};  // uniform
  const float bbeta = b_beta[0];
  const unsigned wbq_l = wbq[lane];       // Wb_h i8, dims 4*lane..4*lane+3
  const float wbsc = wbscale[0];          // folded (amax/127)*(1/127)

  // ---- init ----
  if (tid < 64) hq[tid] = 0u;
  float v = 0.0f, h_old = 0.0f;
  float* betas = out + BATCH;
  const float2* xg2 = reinterpret_cast<const float2*>(x + (size_t)b * TLEN * 2);
  float2 xv = xg2[0];
  __syncthreads();

  for (int t = 0; t < TLEN; ++t) {
    // ---- loop-carried pin: forbids rematerializing the weight loads ----
    asm volatile("" : "+v"(w[0].x),  "+v"(w[0].y),  "+v"(w[0].z),  "+v"(w[0].w),
                      "+v"(w[1].x),  "+v"(w[1].y),  "+v"(w[1].z),  "+v"(w[1].w),
                      "+v"(w[2].x),  "+v"(w[2].y),  "+v"(w[2].z),  "+v"(w[2].w),
                      "+v"(w[3].x),  "+v"(w[3].y),  "+v"(w[3].z),  "+v"(w[3].w));
    asm volatile("" : "+v"(w[4].x),  "+v"(w[4].y),  "+v"(w[4].z),  "+v"(w[4].w),
                      "+v"(w[5].x),  "+v"(w[5].y),  "+v"(w[5].z),  "+v"(w[5].w),
                      "+v"(w[6].x),  "+v"(w[6].y),  "+v"(w[6].z),  "+v"(w[6].w),
                      "+v"(w[7].x),  "+v"(w[7].y),  "+v"(w[7].z),  "+v"(w[7].w));
    asm volatile("" : "+v"(w[8].x),  "+v"(w[8].y),  "+v"(w[8].z),  "+v"(w[8].w),
                      "+v"(w[9].x),  "+v"(w[9].y),  "+v"(w[9].z),  "+v"(w[9].w),
                      "+v"(w[10].x), "+v"(w[10].y), "+v"(w[10].z), "+v"(w[10].w),
                      "+v"(w[11].x), "+v"(w[11].y), "+v"(w[11].z), "+v"(w[11].w));
    asm volatile("" : "+v"(w[12].x), "+v"(w[12].y), "+v"(w[12].z), "+v"(w[12].w),
                      "+v"(w[13].x), "+v"(w[13].y), "+v"(w[13].z), "+v"(w[13].w),
                      "+v"(w[14].x), "+v"(w[14].y), "+v"(w[14].z), "+v"(w[14].w),
                      "+v"(w[15].x), "+v"(w[15].y), "+v"(w[15].z), "+v"(w[15].w));

    // ---- phase 1a: per-wave hWb from h_{t-1} i8 words (hides under burst) --
    const unsigned hw_l = reinterpret_cast<const unsigned*>(hq)[lane];
    int hwb_i = SDOT4(hw_l, wbq_l, 0);
    hwb_i = wave_sum63_i(hwb_i);

    // ---- phase 1b: i8 matvec burst, 4 accumulators ----
    const int4* hb = reinterpret_cast<const int4*>(hq);   // 16 x int4, uniform
    int a0 = 0, a1 = 0, a2 = 0, a3 = 0;
#pragma unroll
    for (int c = 0; c < 4; ++c) {
      const int4 h0 = hb[4 * c + 0];
      const int4 h1 = hb[4 * c + 1];
      const int4 h2 = hb[4 * c + 2];
      const int4 h3 = hb[4 * c + 3];
      a0 = SDOT4(h0.x, w[4 * c + 0].x, a0);
      a1 = SDOT4(h1.x, w[4 * c + 1].x, a1);
      a2 = SDOT4(h2.x, w[4 * c + 2].x, a2);
      a3 = SDOT4(h3.x, w[4 * c + 3].x, a3);
      a0 = SDOT4(h0.y, w[4 * c + 0].y, a0);
      a1 = SDOT4(h1.y, w[4 * c + 1].y, a1);
      a2 = SDOT4(h2.y, w[4 * c + 2].y, a2);
      a3 = SDOT4(h3.y, w[4 * c + 3].y, a3);
      a0 = SDOT4(h0.z, w[4 * c + 0].z, a0);
      a1 = SDOT4(h1.z, w[4 * c + 1].z, a1);
      a2 = SDOT4(h2.z, w[4 * c + 2].z, a2);
      a3 = SDOT4(h3.z, w[4 * c + 3].z, a3);
      a0 = SDOT4(h0.w, w[4 * c + 0].w, a0);
      a1 = SDOT4(h1.w, w[4 * c + 1].w, a1);
      a2 = SDOT4(h2.w, w[4 * c + 2].w, a2);
      a3 = SDOT4(h3.w, w[4 * c + 3].w, a3);
    }
    const int a = (a0 + a1) + (a2 + a3);
    const float ga = fmaf((float)a, sc, bhh);       // hidden projection, this row

    // ---- phase 1c: beta + momentum + r/z sigma ----
    const float hWb = (float)__builtin_amdgcn_readlane(hwb_i, 63) * wbsc;
    const half2_t x2 = half2_t{(_Float16)xv.x, (_Float16)xv.y};
    xv = xg2[(t + 1 < TLEN) ? t + 1 : t];           // prefetch next x
    const float beta = fast_sigmoid(dot2acc(x2, wbx2, hWb + bbeta));
    v = beta * v + dot2acc(x2, wih2, bih);
    if (tid == 0) betas[(size_t)b * TLEN + t] = beta;

    if (g < 2) rz2[d][g] = fast_sigmoid(v + ga);    // r,z -> LDS
    __syncthreads();

    // ---- phase 2 (n-waves only): n, h', quantize ----
    if (g == 2) {
      const float2 rzv = *reinterpret_cast<const float2*>(&rz2[d][0]);  // b64
      const float n_ = fast_tanh(fmaf(rzv.x, ga, v));
      h_old = fmaf(rzv.y, h_old - n_, n_);          // (1-z)n + z h
      const int q = (int)rintf(h_old * 127.0f);
      reinterpret_cast<unsigned char*>(hq)[d] = (unsigned char)(q & 0xff);
    }
    __syncthreads();
  }

  // ---- head (h_T lives in the n-waves) ----
  if (g == 2) {
    float hp = h_old * W_head[d];
    hp = wave_sum63_f(hp);
    if (lane == 63) headred[wv - 8] = hp;
  }
  __syncthreads();
  if (tid == 0)
    out[b] = ((headred[0] + headred[1]) + (headred[2] + headred[3])) + b_head[0];
}

extern "C" void kernel_launch(void* const* d_in, const int* in_sizes, int n_in,
                              void* d_out, int out_size, void* d_ws, size_t ws_size,
                              hipStream_t stream) {
  const float* x      = (const float*)d_in[0];
  const float* W_ih   = (const float*)d_in[1];
  const float* W_hh   = (const float*)d_in[2];
  const float* b_ih   = (const float*)d_in[3];
  const float* b_hh   = (const float*)d_in[4];
  const float* Wb_x   = (const float*)d_in[5];
  const float* Wb_h   = (const float*)d_in[6];
  const float* b_beta = (const float*)d_in[7];
  const float* s      = (const float*)d_in[8];
  const float* W_head = (const float*)d_in[9];
  const float* b_head = (const float*)d_in[10];
  float* out = (float*)d_out;

  char* wsb = (char*)d_ws;
  uint4*    wq      = (uint4*)wsb;                 // 768*16*16 = 196608 B
  float*    scales  = (float*)(wsb + 196608);      // 768*4 = 3072 B
  unsigned* wbq     = (unsigned*)(wsb + 199680);   // 64*4 = 256 B
  float*    wbscale = (float*)(wsb + 199936);      // 4 B

  quant_whh<<<dim3(4), dim3(256), 0, stream>>>(W_hh, Wb_h, wq, scales, wbq, wbscale);
  momgru_persistent<<<dim3(BATCH), dim3(768), 0, stream>>>(
      x, W_ih, b_ih, b_hh, Wb_x, b_beta, s, W_head, b_head,
      (const uint4*)wq, (const float*)scales, (const unsigned*)wbq,
      (const float*)wbscale, out);
}